// Round 12
// baseline (66.360 us; speedup 1.0000x reference)
//
#include <hip/hip_runtime.h>
#include <hip/hip_bf16.h>

// out[m, p*64+q] = sum_{k,l} x[m, k*64+l] * A[p,k] * B[q,l] + bias[p*64+q]
// Per row m: U = X * B^T (contract l), then out_tile^T = U^T * A^T (contract k).
// One wave per row, 8192 waves. MFMA 16x16x32 bf16, fp32 accumulate.
// Round 12 (base = R11, two micro-fixes aimed at the wave tail):
//  (1) chunk-U swizzle (q&3)<<4 -> (q&7)<<4: R11's swizzle left lanes
//      lr/lr+4/lr+8/lr+12 on identical banks (4-way conflict, 1.58x LDS);
//      q&7 reduces to 2-way (free). Bijective, alignment-preserving.
//  (2) bias folded into the stage-2 MFMA C-initializer: bias loads move off
//      the store path (were 16 x ~200cy L2 latency right before the NT
//      stores) and hide under the MFMA cluster; readback->store is now pure.

typedef __bf16 bf16x8 __attribute__((ext_vector_type(8)));
typedef __bf16 bf16x4 __attribute__((ext_vector_type(4)));
typedef float  f32x4  __attribute__((ext_vector_type(4)));

#define MFMA16(Aop, Bop, C) __builtin_amdgcn_mfma_f32_16x16x32_bf16(Aop, Bop, C, 0, 0, 0)

__device__ __forceinline__ bf16x8 load_cvt8(const float* __restrict__ p) {
    const float4 a = *reinterpret_cast<const float4*>(p);
    const float4 b = *reinterpret_cast<const float4*>(p + 4);
    bf16x8 r;
    r[0] = (__bf16)a.x; r[1] = (__bf16)a.y; r[2] = (__bf16)a.z; r[3] = (__bf16)a.w;
    r[4] = (__bf16)b.x; r[5] = (__bf16)b.y; r[6] = (__bf16)b.z; r[7] = (__bf16)b.w;
    return r;
}

__global__ __launch_bounds__(256, 4)
void kron_linear_kernel(const float* __restrict__ x,
                        const float* __restrict__ A,
                        const float* __restrict__ B,
                        const float* __restrict__ bias,
                        float* __restrict__ out) {
    // ONE 4 KB buffer per wave, reused in sequence:
    //  (a) U chunk 0: U[k][q], k in [0,32)   (bf16, k-contiguous, swizzled)
    //  (b) U chunk 1: U[k][q], k in [32,64)
    //  (c) 16x64 f32 output quarter-tiles (4 of them)
    __shared__ __align__(16) char Ulds[4][4096];

    const int lane = threadIdx.x & 63;
    const int wv   = threadIdx.x >> 6;    // wave in block, 0..3
    const int lr   = lane & 15;           // lane % 16
    const int hi   = lane >> 4;           // 0..3
    const int m    = blockIdx.x * 4 + wv; // row id, 0..8191

    char* ubase = &Ulds[wv][0];
    const float* xrow = x + (size_t)m * 4096;

    // ---- Constant fragments ----
    // Af[t][kt]: lane holds A[16t+lr][32kt + 8hi + j]   (stage-2 B-operand = A^T)
    // Bf[t][kt]: lane holds B[16t+lr][32kt + 8hi + j]   (stage-1 B-operand)
    bf16x8 Af[4][2], Bf[4][2];
    #pragma unroll
    for (int t = 0; t < 4; ++t) {
        #pragma unroll
        for (int kt = 0; kt < 2; ++kt) {
            const int row = 16 * t + lr;
            const int c0  = 32 * kt + 8 * hi;
            Af[t][kt] = load_cvt8(A + row * 64 + c0);
            Bf[t][kt] = load_cvt8(B + row * 64 + c0);
        }
    }

    // ---- X fragments: stage-1 A-operand. lane holds X[16mt+lr][32kt+8hi+j] ----
    bf16x8 Xf[4][2];
    #pragma unroll
    for (int mt = 0; mt < 4; ++mt) {
        #pragma unroll
        for (int kt = 0; kt < 2; ++kt) {
            Xf[mt][kt] = load_cvt8(xrow + (16 * mt + lr) * 64 + 32 * kt + 8 * hi);
        }
    }

    // ---- Stage 1 + U transpose, k-chunked through the 4 KB buffer.
    // Chunk c holds U[k][q], k in [32c, 32c+32). Byte off (local k'):
    // off = q*64 + k'*2, XOR-swizzled by ((q&7)<<4)  [2-way max, free].
    // Write side: lane's r-th C/D value is U[16mt + 4hi + r][16nt + lr].
    // Read side (Uf[c][qt]): lane reads U[32c + 8hi + j][16qt + lr], j=0..7,
    // one ds_read_b128 at off = q*64 + 16*hi (16B-aligned, swizzle-safe). ----
    bf16x8 Uf[2][4];
    #pragma unroll
    for (int c = 0; c < 2; ++c) {
        if (c == 1) {
            // Chunk-0 fragment reads must complete before overwrite.
            asm volatile("s_waitcnt lgkmcnt(0)" ::: "memory");
        }
        #pragma unroll
        for (int mtl = 0; mtl < 2; ++mtl) {
            const int mt = 2 * c + mtl;
            #pragma unroll
            for (int nt = 0; nt < 4; ++nt) {
                f32x4 u = {0.f, 0.f, 0.f, 0.f};
                u = MFMA16(Xf[mt][0], Bf[nt][0], u);
                u = MFMA16(Xf[mt][1], Bf[nt][1], u);
                const int q   = 16 * nt + lr;
                const int kl  = 16 * mtl + 4 * hi;   // k within chunk
                const int off = (q * 64 + kl * 2) ^ ((q & 7) << 4);
                bf16x4 v;
                v[0] = (__bf16)u[0];
                v[1] = (__bf16)u[1];
                v[2] = (__bf16)u[2];
                v[3] = (__bf16)u[3];
                *reinterpret_cast<bf16x4*>(ubase + off) = v;
            }
        }
        asm volatile("s_waitcnt lgkmcnt(0)" ::: "memory");
        #pragma unroll
        for (int qt = 0; qt < 4; ++qt) {
            const int q   = 16 * qt + lr;
            const int off = (q * 64 + 16 * hi) ^ ((q & 7) << 4);
            Uf[c][qt] = *reinterpret_cast<const bf16x8*>(ubase + off);
        }
    }
    // Chunk-1 fragment data must be in registers before out-staging reuses
    // the buffer.
    asm volatile("s_waitcnt lgkmcnt(0)" ::: "memory");

    // ---- Stage 2 (transposed): D[q][p] = sum_k U^T[q][k] * A^T[k][p],
    // with C initialized to the bias tile (bias[(16h+lr)*64 + 16qt+4hi + r]
    // matches lane's r-th D value = out[p=16h+lr][q=16qt+4hi+r]).
    // Stage each 16-row quarter-tile (4 KB f32) in LDS, then stream it out
    // linearly: one instruction = 64 lanes x 16B = 1 KB contiguous. ----
    float* orow = out + (size_t)m * 4096;
    #pragma unroll
    for (int h = 0; h < 4; ++h) {
        #pragma unroll
        for (int qt = 0; qt < 4; ++qt) {
            const int p  = 16 * h + lr;
            const int q0 = 16 * qt + 4 * hi;
            f32x4 acc = *reinterpret_cast<const f32x4*>(bias + p * 64 + q0);
            acc = MFMA16(Uf[0][qt], Af[h][0], acc);
            acc = MFMA16(Uf[1][qt], Af[h][1], acc);
            const int off = (lr * 256 + q0 * 4) ^ ((lr & 7) << 4);
            *reinterpret_cast<f32x4*>(ubase + off) = acc;
        }
        asm volatile("s_waitcnt lgkmcnt(0)" ::: "memory");

        // Linear read-back: lane reads row pp = 4i+hi, 16B at col 4*lane;
        // bias already included -> straight NT store.
        #pragma unroll
        for (int i = 0; i < 4; ++i) {
            const int pp  = 4 * i + hi;
            const int off = (i * 1024 + lane * 16) ^ ((pp & 7) << 4);
            const f32x4 v = *reinterpret_cast<const f32x4*>(ubase + off);
            const int col = 1024 * h + i * 256 + lane * 4;
            __builtin_nontemporal_store(v, reinterpret_cast<f32x4*>(orow + col));
        }
        // Quarter-tile reads must complete before the next quarter overwrites.
        asm volatile("s_waitcnt lgkmcnt(0)" ::: "memory");
    }
}

extern "C" void kernel_launch(void* const* d_in, const int* in_sizes, int n_in,
                              void* d_out, int out_size, void* d_ws, size_t ws_size,
                              hipStream_t stream) {
    const float* x    = (const float*)d_in[0];
    const float* A    = (const float*)d_in[1];
    const float* B    = (const float*)d_in[2];
    const float* bias = (const float*)d_in[3];
    float* out        = (float*)d_out;

    // 2048 blocks x 4 waves = 8192 waves, one output row each.
    // 16 KB LDS/block + VGPR ~64 -> 8 blocks/CU = full 32 waves/CU residency.
    kron_linear_kernel<<<dim3(2048), dim3(256), 0, stream>>>(x, A, B, bias, out);
}

// Round 13
// 57.557 us; speedup vs baseline: 1.1530x; 1.1530x over previous
//
#include <hip/hip_runtime.h>
#include <hip/hip_bf16.h>

// out[m, p*64+q] = sum_{k,l} x[m, k*64+l] * A[p,k] * B[q,l] + bias[p*64+q]
// Per row m: U = X * B^T (contract l), then out_tile^T = U^T * A^T (contract k).
// One wave per row, 8192 waves. MFMA 16x16x32 bf16, fp32 accumulate.
// Round 13 = Round 11 (best known, 57.9us) + ONLY the verified swizzle fix:
//   chunk-U swizzle (q&3)<<4 -> (q&7)<<4  [R12: conflicts 1.83M -> 786K].
// R12's bias-as-C-init is REVERTED: initializing the MFMA accumulator from a
// global load couples L1/L2 latency into the MFMA dependency chain (wave
// stalls on vmcnt before every stage-2 MFMA pair). Bias stays in the
// epilogue where its latency overlaps the LDS readback + NT stores.

typedef __bf16 bf16x8 __attribute__((ext_vector_type(8)));
typedef __bf16 bf16x4 __attribute__((ext_vector_type(4)));
typedef float  f32x4  __attribute__((ext_vector_type(4)));

#define MFMA16(Aop, Bop, C) __builtin_amdgcn_mfma_f32_16x16x32_bf16(Aop, Bop, C, 0, 0, 0)

__device__ __forceinline__ bf16x8 load_cvt8(const float* __restrict__ p) {
    const float4 a = *reinterpret_cast<const float4*>(p);
    const float4 b = *reinterpret_cast<const float4*>(p + 4);
    bf16x8 r;
    r[0] = (__bf16)a.x; r[1] = (__bf16)a.y; r[2] = (__bf16)a.z; r[3] = (__bf16)a.w;
    r[4] = (__bf16)b.x; r[5] = (__bf16)b.y; r[6] = (__bf16)b.z; r[7] = (__bf16)b.w;
    return r;
}

__global__ __launch_bounds__(256, 4)
void kron_linear_kernel(const float* __restrict__ x,
                        const float* __restrict__ A,
                        const float* __restrict__ B,
                        const float* __restrict__ bias,
                        float* __restrict__ out) {
    // ONE 4 KB buffer per wave, reused in sequence:
    //  (a) U chunk 0: U[k][q], k in [0,32)   (bf16, k-contiguous, swizzled)
    //  (b) U chunk 1: U[k][q], k in [32,64)
    //  (c) 16x64 f32 output quarter-tiles (4 of them)
    __shared__ __align__(16) char Ulds[4][4096];

    const int lane = threadIdx.x & 63;
    const int wv   = threadIdx.x >> 6;    // wave in block, 0..3
    const int lr   = lane & 15;           // lane % 16
    const int hi   = lane >> 4;           // 0..3
    const int m    = blockIdx.x * 4 + wv; // row id, 0..8191

    char* ubase = &Ulds[wv][0];
    const float* xrow = x + (size_t)m * 4096;

    // ---- Constant fragments ----
    // Af[t][kt]: lane holds A[16t+lr][32kt + 8hi + j]   (stage-2 B-operand = A^T)
    // Bf[t][kt]: lane holds B[16t+lr][32kt + 8hi + j]   (stage-1 B-operand)
    bf16x8 Af[4][2], Bf[4][2];
    #pragma unroll
    for (int t = 0; t < 4; ++t) {
        #pragma unroll
        for (int kt = 0; kt < 2; ++kt) {
            const int row = 16 * t + lr;
            const int c0  = 32 * kt + 8 * hi;
            Af[t][kt] = load_cvt8(A + row * 64 + c0);
            Bf[t][kt] = load_cvt8(B + row * 64 + c0);
        }
    }

    // ---- X fragments: stage-1 A-operand. lane holds X[16mt+lr][32kt+8hi+j] ----
    bf16x8 Xf[4][2];
    #pragma unroll
    for (int mt = 0; mt < 4; ++mt) {
        #pragma unroll
        for (int kt = 0; kt < 2; ++kt) {
            Xf[mt][kt] = load_cvt8(xrow + (16 * mt + lr) * 64 + 32 * kt + 8 * hi);
        }
    }

    // ---- Stage 1 + U transpose, k-chunked through the 4 KB buffer.
    // Chunk c holds U[k][q], k in [32c, 32c+32). Byte off (local k'):
    // off = q*64 + k'*2, XOR-swizzled by ((q&7)<<4)  [2-way max, free].
    // Write side: lane's r-th C/D value is U[16mt + 4hi + r][16nt + lr].
    // Read side (Uf[c][qt]): lane reads U[32c + 8hi + j][16qt + lr], j=0..7,
    // one ds_read_b128 at off = q*64 + 16*hi (16B-aligned, swizzle-safe). ----
    bf16x8 Uf[2][4];
    #pragma unroll
    for (int c = 0; c < 2; ++c) {
        if (c == 1) {
            // Chunk-0 fragment reads must complete before overwrite.
            asm volatile("s_waitcnt lgkmcnt(0)" ::: "memory");
        }
        #pragma unroll
        for (int mtl = 0; mtl < 2; ++mtl) {
            const int mt = 2 * c + mtl;
            #pragma unroll
            for (int nt = 0; nt < 4; ++nt) {
                f32x4 u = {0.f, 0.f, 0.f, 0.f};
                u = MFMA16(Xf[mt][0], Bf[nt][0], u);
                u = MFMA16(Xf[mt][1], Bf[nt][1], u);
                const int q   = 16 * nt + lr;
                const int kl  = 16 * mtl + 4 * hi;   // k within chunk
                const int off = (q * 64 + kl * 2) ^ ((q & 7) << 4);
                bf16x4 v;
                v[0] = (__bf16)u[0];
                v[1] = (__bf16)u[1];
                v[2] = (__bf16)u[2];
                v[3] = (__bf16)u[3];
                *reinterpret_cast<bf16x4*>(ubase + off) = v;
            }
        }
        asm volatile("s_waitcnt lgkmcnt(0)" ::: "memory");
        #pragma unroll
        for (int qt = 0; qt < 4; ++qt) {
            const int q   = 16 * qt + lr;
            const int off = (q * 64 + 16 * hi) ^ ((q & 7) << 4);
            Uf[c][qt] = *reinterpret_cast<const bf16x8*>(ubase + off);
        }
    }
    // Chunk-1 fragment data must be in registers before out-staging reuses
    // the buffer.
    asm volatile("s_waitcnt lgkmcnt(0)" ::: "memory");

    // ---- Stage 2 (transposed): D[q][p] = sum_k U^T[q][k] * A^T[k][p].
    // Lane's r-th acc value is out[p=16h+lr][q=16qt+4hi+r]. Stage each
    // 16-row quarter-tile (4 KB f32) in LDS, then stream it out linearly:
    // one instruction = 64 lanes x 16B = 1 KB contiguous.
    // Staging off = pp*256 + q0*4, swizzled by ((pp&7)<<4), pp = row in tile. ----
    float* orow = out + (size_t)m * 4096;
    #pragma unroll
    for (int h = 0; h < 4; ++h) {
        #pragma unroll
        for (int qt = 0; qt < 4; ++qt) {
            f32x4 acc = {0.f, 0.f, 0.f, 0.f};
            acc = MFMA16(Uf[0][qt], Af[h][0], acc);
            acc = MFMA16(Uf[1][qt], Af[h][1], acc);
            const int pp  = lr;                  // row within quarter-tile
            const int q0  = 16 * qt + 4 * hi;
            const int off = (pp * 256 + q0 * 4) ^ ((pp & 7) << 4);
            *reinterpret_cast<f32x4*>(ubase + off) = acc;
        }
        asm volatile("s_waitcnt lgkmcnt(0)" ::: "memory");

        // Linear read-back: lane reads row pp = 4i+hi, 16B at col 4*lane;
        // bias added here (off the MFMA chain), then NT store.
        #pragma unroll
        for (int i = 0; i < 4; ++i) {
            const int pp  = 4 * i + hi;
            const int off = (i * 1024 + lane * 16) ^ ((pp & 7) << 4);
            const f32x4 v = *reinterpret_cast<const f32x4*>(ubase + off);
            const int col = 1024 * h + i * 256 + lane * 4;
            const f32x4 bv = *reinterpret_cast<const f32x4*>(bias + col);
            f32x4 o;
            o[0] = v[0] + bv[0];
            o[1] = v[1] + bv[1];
            o[2] = v[2] + bv[2];
            o[3] = v[3] + bv[3];
            __builtin_nontemporal_store(o, reinterpret_cast<f32x4*>(orow + col));
        }
        // Quarter-tile reads must complete before the next quarter overwrites.
        asm volatile("s_waitcnt lgkmcnt(0)" ::: "memory");
    }
}

extern "C" void kernel_launch(void* const* d_in, const int* in_sizes, int n_in,
                              void* d_out, int out_size, void* d_ws, size_t ws_size,
                              hipStream_t stream) {
    const float* x    = (const float*)d_in[0];
    const float* A    = (const float*)d_in[1];
    const float* B    = (const float*)d_in[2];
    const float* bias = (const float*)d_in[3];
    float* out        = (float*)d_out;

    // 2048 blocks x 4 waves = 8192 waves, one output row each.
    // 16 KB LDS/block + VGPR 64 -> 8 blocks/CU = full-residency geometry.
    kron_linear_kernel<<<dim3(2048), dim3(256), 0, stream>>>(x, A, B, bias, out);
}